// Round 2
// baseline (677.062 us; speedup 1.0000x reference)
//
#include <hip/hip_runtime.h>

// Problem constants (from reference): inputs (16, 512, 64, 192) fp32
constexpr int Bq = 16;
constexpr int Cc = 256;          // channels per half (x1 / x2)
constexpr int Hh = 64;
constexpr int Ww = 192;
constexpr int Dd = 25;           // MAX_DISP + 1
constexpr int HW = Hh * Ww;      // 12288 (channel stride)
constexpr int BSTRIDE = 2 * Cc * HW;  // batch stride in floats
constexpr int CPR = 4;           // channels staged per round
constexpr int NR = Cc / CPR;     // 64 rounds
constexpr int ROWP = 24 + Ww;    // LDS row: 24-zero left pad + 192 data
constexpr int HT = 4;            // output rows per block
constexpr int RT = HT + 2;       // corr rows computed per block (halo above/below)
constexpr int TW = Ww + 4;       // box tile row: [0,1]=left zero pad, [2..193]=w, [194,195]=right pad
constexpr int NTHREADS = RT * 96;  // 576 threads = 9 waves

// Fused kernel: corr (over 256 channels, 25 disparities) + 3x3 all-ones box
// filter, no workspace. Block covers RT=6 corr rows (4 output + 2 halo),
// each lane owns (row r, w0=2u, w0+1) and 25 float2 accumulators.
//
// ROUND 2 = MEASUREMENT ROUND: kernel body is IDENTICAL to round 1; the
// launcher runs it twice (idempotent: reads `in`, writes `out` only).
// dur_us(R2) - dur_us(R1) = exact single-kernel duration, independent of the
// harness's workspace-poison fills that dominate the timed region.
__global__ __launch_bounds__(NTHREADS) void fused_kernel(const float* __restrict__ in,
                                                         float* __restrict__ out) {
  const int t  = threadIdx.x;
  const int r  = t / 96;          // 0..5 (corr row within block)
  const int u  = t % 96;
  const int w0 = 2 * u;

  // XCD-aware decode: adjacent h-tiles of the same b land on the same XCD
  // (default xcd = lin % 8 round-robin), so halo rows re-hit that XCD's L2.
  const int lin  = blockIdx.x;    // 0..255
  const int slot = lin & 7;
  const int jj   = lin >> 3;      // 0..31
  const int b    = slot + 8 * (jj >> 4);
  const int tile = jj & 15;
  const int hbase = tile * HT;
  const int h = hbase + r - 1;    // corr row in [-1, 64]
  const bool hvalid = (h >= 0) && (h < Hh);
  const int hc = hvalid ? h : 0;  // clamped for safe address arithmetic

  // LDS reused across phases: staging buffer (5184 floats) then box tile (1176).
  __shared__ float lds[RT * CPR * ROWP];
  auto x2s   = (float (*)[CPR][ROWP])lds;
  auto tilep = (float (*)[TW])lds;

  // Zero the 24-float left pads once: RT*CPR*24 = 576 writes = blockDim exactly.
  {
    const int rr  = t / (CPR * 24);
    const int rem = t % (CPR * 24);
    x2s[rr][rem / 24][rem % 24] = 0.0f;
  }

  const float* x1p = in + (size_t)b * BSTRIDE + (size_t)hc * Ww + w0;
  const float* x2p = x1p + (size_t)Cc * HW;

  float2 acc[Dd];
#pragma unroll
  for (int d = 0; d < Dd; ++d) acc[d] = make_float2(0.0f, 0.0f);

  // Prefetch round 0 (invalid halo rows contribute zeros => zero-padded conv in h)
  float2 px1[CPR], px2[CPR];
#pragma unroll
  for (int c = 0; c < CPR; ++c) {
    if (hvalid) {
      px1[c] = *(const float2*)(x1p + c * HW);
      px2[c] = *(const float2*)(x2p + c * HW);
    } else {
      px1[c] = make_float2(0.0f, 0.0f);
      px2[c] = make_float2(0.0f, 0.0f);
    }
  }

  for (int rnd = 0; rnd < NR; ++rnd) {
    __syncthreads();  // previous round finished reading LDS (also covers pad init)
    float2 cx1[CPR];
#pragma unroll
    for (int c = 0; c < CPR; ++c) {
      cx1[c] = px1[c];
      *(float2*)&x2s[r][c][24 + w0] = px2[c];
    }
    __syncthreads();  // staging visible

    // Issue next round's global loads AFTER the barrier so the barrier's
    // vmcnt(0) drain doesn't serialize them; compute below hides latency.
    if (rnd + 1 < NR && hvalid) {
      const float* p1 = x1p + (size_t)(rnd + 1) * CPR * HW;
      const float* p2 = p1 + (size_t)Cc * HW;
#pragma unroll
      for (int c = 0; c < CPR; ++c) {
        px1[c] = *(const float2*)(p1 + c * HW);
        px2[c] = *(const float2*)(p2 + c * HW);
      }
    }

#pragma unroll
    for (int c = 0; c < CPR; ++c) {
      // Sliding window x2[w0-24 .. w0+1] via 13 aligned ds_read_b64
      float win[26];
#pragma unroll
      for (int k = 0; k < 13; ++k) {
        const float2 v = *(const float2*)&x2s[r][c][w0 + 2 * k];
        win[2 * k]     = v.x;
        win[2 * k + 1] = v.y;
      }
      const float a0 = cx1[c].x, a1 = cx1[c].y;
#pragma unroll
      for (int d = 0; d < Dd; ++d) {
        acc[d].x = fmaf(a0, win[24 - d], acc[d].x);
        acc[d].y = fmaf(a1, win[25 - d], acc[d].y);
      }
    }
  }

  // ---- box-filter phase: per d, stage 6x192 corr rows in LDS, 3x3 sum ----
  float* outb = out + (size_t)b * Dd * Hh * Ww;
#pragma unroll
  for (int d = 0; d < Dd; ++d) {
    __syncthreads();  // prior LDS reads (accum phase or previous d) done
    *(float2*)&tilep[r][2 + w0] = acc[d];
    if (u == 0)  { tilep[r][0]      = 0.0f; tilep[r][1]      = 0.0f; }
    if (u == 95) { tilep[r][TW - 2] = 0.0f; tilep[r][TW - 1] = 0.0f; }
    __syncthreads();
    if (r < HT) {
      // output row hbase+r needs corr rows (tile rows) r, r+1, r+2
      float sx = 0.0f, sy = 0.0f;
#pragma unroll
      for (int q = 0; q < 3; ++q) {
        const float* trow = tilep[r + q];
        const float2 A = *(const float2*)&trow[w0];       // cols w0-2, w0-1
        const float2 B = *(const float2*)&trow[w0 + 2];   // cols w0,   w0+1
        const float2 C = *(const float2*)&trow[w0 + 4];   // cols w0+2, w0+3
        sx += A.y + B.x + B.y;
        sy += B.x + B.y + C.x;
      }
      *(float2*)(outb + ((size_t)d * Hh + hbase + r) * Ww + w0) = make_float2(sx, sy);
    }
  }
}

extern "C" void kernel_launch(void* const* d_in, const int* in_sizes, int n_in,
                              void* d_out, int out_size, void* d_ws, size_t ws_size,
                              hipStream_t stream) {
  const float* in = (const float*)d_in[0];
  float* out = (float*)d_out;
  (void)d_ws; (void)ws_size;  // workspace intentionally unused

  // MEASUREMENT: launch twice (idempotent). dur_us delta vs round 1 gives the
  // exact per-launch kernel time, disambiguating harness-fill overhead.
  fused_kernel<<<dim3(Bq * (Hh / HT)), dim3(NTHREADS), 0, stream>>>(in, out);
  fused_kernel<<<dim3(Bq * (Hh / HT)), dim3(NTHREADS), 0, stream>>>(in, out);
}

// Round 3
// 622.651 us; speedup vs baseline: 1.0874x; 1.0874x over previous
//
#include <hip/hip_runtime.h>

// Problem constants (from reference): inputs (16, 512, 64, 192) fp32
constexpr int Bq = 16;
constexpr int Cc = 256;          // channels per half (x1 / x2)
constexpr int Hh = 64;
constexpr int Ww = 192;
constexpr int Dd = 25;           // MAX_DISP + 1
constexpr int HW = Hh * Ww;      // 12288 (channel stride)
constexpr int BSTRIDE = 2 * Cc * HW;  // batch stride in floats
constexpr int CPR = 4;           // channels staged per half per round
constexpr int NR2 = (Cc / 2) / CPR;   // 32 rounds (each half does 128 channels)
constexpr int HT = 4;            // output rows per block
constexpr int RT = HT + 2;       // 6 corr rows (halo above/below)
constexpr int ROWP = 24 + Ww;    // 216: 24-zero left pad + 192 data
constexpr int TW = 200;          // box tile row: [0,1] pad, [2..193] data, [194,195] pad, +4 align
constexpr int NTHREADS = 576;    // 2 channel-halves x 6 rows x 48 lanes (4 outputs each)

// Fused corr + 3x3 box. Each thread: 4 w-outputs (w0=4u), one channel half,
// 25 float4 accumulators. Window redundancy cut ~2x vs 2-output version
// (28 floats read per 4 outputs per channel instead of 26 per 2).
__global__ __launch_bounds__(NTHREADS, 3) void fused_kernel(const float* __restrict__ in,
                                                            float* __restrict__ out) {
  const int t  = threadIdx.x;
  const int p  = t / 288;        // channel half: 0 -> c 0..127, 1 -> c 128..255
  const int s  = t % 288;
  const int r  = s / 48;         // corr row within block, 0..5
  const int u  = s % 48;
  const int w0 = 4 * u;

  // XCD-aware decode: adjacent h-tiles of the same b share an XCD L2 (halo reuse)
  const int lin  = blockIdx.x;   // 0..255
  const int slot = lin & 7;
  const int jj   = lin >> 3;     // 0..31
  const int b    = slot + 8 * (jj >> 4);
  const int tile = jj & 15;
  const int hbase = tile * HT;
  const int h = hbase + r - 1;   // corr row in [-1, 64]
  const bool hvalid = (h >= 0) && (h < Hh);
  const int hc = hvalid ? h : 0;

  // LDS reused across phases:
  //   main loop: x2 staging [2][6][4][216]   (41.5 KB)
  //   merge:     [288][7] float4             (32.3 KB)
  //   box:       [6][200] float              (4.8 KB)
  __shared__ float lds[2 * RT * CPR * ROWP];
  auto x2s   = (float (*)[RT][CPR][ROWP])lds;
  auto mrg   = (float4 (*)[7])lds;
  auto tilep = (float (*)[TW])lds;

  // Zero the 24-float left pads once: 2*6*4*12 float2 = 576 writes = blockDim.
  {
    const int pz  = t / 288;
    const int g   = t % 288;
    const int rz  = g / 48;
    const int rem = g % 48;
    const int cz  = rem / 12;
    const int jz  = rem % 12;
    *(float2*)&x2s[pz][rz][cz][2 * jz] = make_float2(0.0f, 0.0f);
  }

  // x2 staging slot descriptors: 4608 floats per half per round = 288 thr x 4 float4.
  const float* gx2[4];
  bool v2[4];
  float* ldst[4];
#pragma unroll
  for (int k = 0; k < 4; ++k) {
    const int lf = (k * 288 + s) * 4;      // 0..4604
    const int rk = lf / 768;               // staged row 0..5
    const int ck = (lf % 768) / 192;       // channel-within-round 0..3
    const int wk = lf % 192;               // w (multiple of 4)
    const int hk = hbase + rk - 1;
    v2[k] = (hk >= 0) && (hk < Hh);
    const int hck = v2[k] ? hk : 0;
    gx2[k]  = in + (size_t)b * BSTRIDE + (size_t)(Cc + 128 * p + ck) * HW
                 + (size_t)hck * Ww + wk;
    ldst[k] = &x2s[p][rk][ck][24 + wk];
  }

  float4 acc[Dd];
#pragma unroll
  for (int d = 0; d < Dd; ++d) acc[d] = make_float4(0.f, 0.f, 0.f, 0.f);

  // Prefetch round 0 staging data (halo rows -> zeros: zero-padded conv in h)
  float4 px2[4];
#pragma unroll
  for (int k = 0; k < 4; ++k)
    px2[k] = v2[k] ? *(const float4*)gx2[k] : make_float4(0.f, 0.f, 0.f, 0.f);

  const float* gx1 = in + (size_t)b * BSTRIDE + (size_t)(128 * p) * HW
                        + (size_t)hc * Ww + w0;

  for (int rnd = 0; rnd < NR2; ++rnd) {
    __syncthreads();  // previous round finished reading LDS (also covers pad init)
#pragma unroll
    for (int k = 0; k < 4; ++k) *(float4*)ldst[k] = px2[k];
    __syncthreads();  // staging visible

    // Issue next round's global loads AFTER the barrier; compute hides latency.
    if (rnd + 1 < NR2) {
#pragma unroll
      for (int k = 0; k < 4; ++k) {
        gx2[k] += (size_t)CPR * HW;
        px2[k] = v2[k] ? *(const float4*)gx2[k] : make_float4(0.f, 0.f, 0.f, 0.f);
      }
    }

    // x1 for this round's 4 channels (private per thread, coalesced float4)
    float4 cx1[CPR];
#pragma unroll
    for (int c = 0; c < CPR; ++c)
      cx1[c] = hvalid ? *(const float4*)(gx1 + (size_t)(rnd * CPR + c) * HW)
                      : make_float4(0.f, 0.f, 0.f, 0.f);

#pragma unroll
    for (int c = 0; c < CPR; ++c) {
      const float4 cx = cx1[c];
      // Window: padded idx w0..w0+27 <-> x2 cols w0-24..w0+3, consumed per float4.
      // j = padded offset - w0; output i uses d = i + 24 - j (static after unroll).
#pragma unroll
      for (int k = 0; k < 7; ++k) {
        const float4 wv = *(const float4*)&x2s[p][r][c][w0 + 4 * k];
#pragma unroll
        for (int e = 0; e < 4; ++e) {
          const int j = 4 * k + e;
          const float we = (e == 0) ? wv.x : (e == 1) ? wv.y : (e == 2) ? wv.z : wv.w;
          const int d0_ = 24 - j;  // d for output i=0
          if (d0_ >= 0 && d0_ <= 24)         acc[d0_].x     = fmaf(cx.x, we, acc[d0_].x);
          if (d0_ + 1 >= 0 && d0_ + 1 <= 24) acc[d0_ + 1].y = fmaf(cx.y, we, acc[d0_ + 1].y);
          if (d0_ + 2 >= 0 && d0_ + 2 <= 24) acc[d0_ + 2].z = fmaf(cx.z, we, acc[d0_ + 2].z);
          if (d0_ + 3 >= 0 && d0_ + 3 <= 24) acc[d0_ + 3].w = fmaf(cx.w, we, acc[d0_ + 3].w);
        }
      }
    }
  }

  // ---- merge channel halves: p=1 ships acc to p=0 in 4 chunks of <=7 d ----
#pragma unroll
  for (int ch = 0; ch < 4; ++ch) {
    const int d0 = ch * 7;
    const int nd = (d0 + 7 <= Dd) ? 7 : (Dd - d0);  // 7,7,7,4
    __syncthreads();
    if (p == 1) {
#pragma unroll
      for (int j = 0; j < 7; ++j)
        if (j < nd) mrg[s][j] = acc[d0 + j];
    }
    __syncthreads();
    if (p == 0) {
#pragma unroll
      for (int j = 0; j < 7; ++j)
        if (j < nd) {
          const float4 v = mrg[s][j];
          acc[d0 + j].x += v.x; acc[d0 + j].y += v.y;
          acc[d0 + j].z += v.z; acc[d0 + j].w += v.w;
        }
    }
  }

  // ---- box-filter phase (p=0 half only): per d, stage 6x192 rows, 3x3 sum ----
  float* outb = out + (size_t)b * Dd * Hh * Ww;
#pragma unroll
  for (int d = 0; d < Dd; ++d) {
    __syncthreads();  // prior LDS reads (merge or previous d) done
    if (p == 0) {
      *(float4*)&tilep[r][2 + w0] = acc[d];
      if (u == 0)  { tilep[r][0]   = 0.0f; tilep[r][1]   = 0.0f; }
      if (u == 47) { tilep[r][194] = 0.0f; tilep[r][195] = 0.0f; }
    }
    __syncthreads();
    if (p == 0 && r < HT) {
      // output row hbase+r needs tile rows r, r+1, r+2; cols w0-1 .. w0+4
      float s0 = 0.f, s1 = 0.f, s2 = 0.f, s3 = 0.f;
#pragma unroll
      for (int q = 0; q < 3; ++q) {
        const float4 L = *(const float4*)&tilep[r + q][w0];      // idx w0..w0+3
        const float4 R = *(const float4*)&tilep[r + q][w0 + 4];  // idx w0+4..w0+7
        s0 += L.y + L.z + L.w;
        s1 += L.z + L.w + R.x;
        s2 += L.w + R.x + R.y;
        s3 += R.x + R.y + R.z;
      }
      *(float4*)(outb + ((size_t)d * Hh + hbase + r) * Ww + w0) =
          make_float4(s0, s1, s2, s3);
    }
  }
}

extern "C" void kernel_launch(void* const* d_in, const int* in_sizes, int n_in,
                              void* d_out, int out_size, void* d_ws, size_t ws_size,
                              hipStream_t stream) {
  const float* in = (const float*)d_in[0];
  float* out = (float*)d_out;
  (void)d_ws; (void)ws_size;  // workspace intentionally unused

  fused_kernel<<<dim3(Bq * (Hh / HT)), dim3(NTHREADS), 0, stream>>>(in, out);
}